// Round 11
// baseline (95.336 us; speedup 1.0000x reference)
//
#include <hip/hip_runtime.h>
#include <hip/hip_bf16.h>

// BiClassifier B=4 N=128 D=768 HID=1024 OUT=2
// R11: TWO kernels total.
// k1 gemm_mfma: fused fp32->bf16 conversion + GEMM + out-init.
//     hid = bf16(stacked inputs) @ bf16(W[sel]).T + b1 (rows<512)
//     64x64 tile, 8 waves = 2 K-halves x 4 space waves, reg-staged
//     (load fp32 -> cvt bf16 -> swizzled ds_write_b128), double-buffered,
//     LDS cross-wave K-reduce, plain stores. First 65536 gids also write
//     out[gid] = bo (replaces out_init kernel).
// k2 pair: 16x16 pair tile x h-range 256, atomicAdd onto bo-initialized out
//     [R7/R10-proven, unchanged]

typedef __attribute__((ext_vector_type(8))) short s16x8;
typedef __attribute__((ext_vector_type(8))) unsigned short u16x8;
typedef __attribute__((ext_vector_type(4))) float f32x4;

#define KP 768
#define BK 64
#define KHALF 384
#define NSTEP (KHALF / BK)   // 6

__device__ __forceinline__ u16x8 cvt8_bf16(float4 a, float4 b) {
    const float f[8] = {a.x, a.y, a.z, a.w, b.x, b.y, b.z, b.w};
    u16x8 r;
    #pragma unroll
    for (int i = 0; i < 8; ++i) {
        __hip_bfloat16 h = __float2bfloat16(f[i]);
        r[i] = *(unsigned short*)&h;
    }
    return r;
}

// 64x64 tile, 512 thr = 8 waves: w>>2 = K-half, w&3 = space wave (2x2 of 32x32).
__global__ __launch_bounds__(512) void gemm_mfma(
    const float* __restrict__ in1, const float* __restrict__ in2,
    const float* __restrict__ W1, const float* __restrict__ W2,
    const float* __restrict__ b1, const float* __restrict__ bo,
    float* __restrict__ hid, float* __restrict__ out)
{
    const int t    = threadIdx.x;
    const int lane = t & 63;
    const int w    = t >> 6;
    const int kh   = w >> 2;        // K-half 0/1
    const int ws   = w & 3;         // space wave
    const int row0 = blockIdx.y * 64;
    const int col0 = blockIdx.x * 64;

    // fused out-init: first 65536 gids write bo (pair runs strictly after us)
    const int gid = (blockIdx.y * 16 + blockIdx.x) * 512 + t;
    if (gid < 65536) {
        *(float2*)&out[(size_t)gid * 2] = make_float2(bo[0], bo[1]);
    }

    const bool first = (row0 < 512);
    const float* __restrict__ Asrc = first ? in1 + (size_t)row0 * 768
                                           : in2 + (size_t)(row0 - 512) * 768;
    const float* __restrict__ Wsrc = (first ? W1 : W2) + (size_t)col0 * 768;

    __shared__ ushort lds[2][2][2][4096];   // [buf][kh][A/W][8KB] = 64KB

    // staging map: srow = t>>3 (0..63), phys chunk = t&7,
    // logical k-chunk = (t&7)^(srow&7)  (so reads use phys = logical^((r&7)<<4))
    const int srow   = t >> 3;
    const int lchunk = (t & 7) ^ (srow & 7);

    // fragment read offsets: phys_byte_in_row = logical ^ ((row&7)<<4)
    const int wr = ws >> 1, wc = ws & 1;
    const int l15 = lane & 15, kg = lane >> 4;
    int aoff[2][2], boff[2][2];   // [kk][frag]
    #pragma unroll
    for (int kk = 0; kk < 2; ++kk)
        #pragma unroll
        for (int f = 0; f < 2; ++f) {
            const int r = wr * 32 + f * 16 + l15;
            const int c = wc * 32 + f * 16 + l15;
            const int sw_ = kk * 64 + kg * 16;
            aoff[kk][f] = r * 128 + (sw_ ^ ((r & 7) << 4));
            boff[kk][f] = c * 128 + (sw_ ^ ((c & 7) << 4));
        }

    // reg-staged loads: p = 0..3 -> (kh_p = p>>1, src = p&1 ? W : A)
    float4 ra[4][2];
#define LOADREGS(ktk) do {                                                     \
        _Pragma("unroll")                                                      \
        for (int p = 0; p < 4; ++p) {                                          \
            const float* s = (p & 1) ? Wsrc : Asrc;                            \
            const size_t off = (size_t)srow * 768 + (p >> 1) * KHALF           \
                               + (ktk) * BK + lchunk * 8;                      \
            ra[p][0] = *(const float4*)(s + off);                              \
            ra[p][1] = *(const float4*)(s + off + 4);                          \
        }                                                                      \
    } while (0)

    const f32x4 zero = {0.f, 0.f, 0.f, 0.f};
    f32x4 acc[2][2] = {{zero, zero}, {zero, zero}};

    LOADREGS(0);
    int cur = 0;
    for (int kt = 0; kt < NSTEP; ++kt) {
        // convert + swizzled LDS write (phys chunk t&7 of row srow)
        #pragma unroll
        for (int p = 0; p < 4; ++p)
            *(u16x8*)((char*)&lds[cur][p >> 1][p & 1][0] + t * 16) =
                cvt8_bf16(ra[p][0], ra[p][1]);
        __syncthreads();
        if (kt + 1 < NSTEP) LOADREGS(kt + 1);   // issue early, hide under MFMA
        const char* __restrict__ ab = (const char*)&lds[cur][kh][0][0];
        const char* __restrict__ wb = (const char*)&lds[cur][kh][1][0];
        #pragma unroll
        for (int kk = 0; kk < 2; ++kk) {
            s16x8 af[2], bf_[2];
            #pragma unroll
            for (int f = 0; f < 2; ++f) {
                af[f]  = *(const s16x8*)(ab + aoff[kk][f]);
                bf_[f] = *(const s16x8*)(wb + boff[kk][f]);
            }
            #pragma unroll
            for (int fr = 0; fr < 2; ++fr)
                #pragma unroll
                for (int fc = 0; fc < 2; ++fc)
                    acc[fr][fc] = __builtin_amdgcn_mfma_f32_16x16x32_bf16(
                        af[fr], bf_[fc], acc[fr][fc], 0, 0, 0);
        }
        __syncthreads();
        cur ^= 1;
    }
#undef LOADREGS

    // cross-wave K-reduce: kh==1 waves park accs in LDS, kh==0 waves fold+store.
    float* red = (float*)&lds[0][0][0][0];
    if (kh == 1) {
        #pragma unroll
        for (int fr = 0; fr < 2; ++fr)
            #pragma unroll
            for (int fc = 0; fc < 2; ++fc)
                *(f32x4*)&red[(((ws * 2 + fr) * 2 + fc) * 64 + lane) * 4] =
                    acc[fr][fc];
    }
    __syncthreads();
    if (kh == 0) {
        float bias[2] = {0.f, 0.f};
        if (first) {
            bias[0] = b1[col0 + wc * 32 + l15];
            bias[1] = b1[col0 + wc * 32 + 16 + l15];
        }
        #pragma unroll
        for (int fr = 0; fr < 2; ++fr)
            #pragma unroll
            for (int fc = 0; fc < 2; ++fc) {
                const f32x4 o = *(const f32x4*)
                    &red[(((ws * 2 + fr) * 2 + fc) * 64 + lane) * 4];
                #pragma unroll
                for (int i = 0; i < 4; ++i) {
                    const int r = row0 + wr * 32 + fr * 16 + kg * 4 + i;
                    const int c = col0 + wc * 32 + fc * 16 + l15;
                    hid[(size_t)r * 1024 + c] = acc[fr][fc][i] + o[i] + bias[fc];
                }
            }
    }
}

// 16x16 pair tile x h-range 256. Grid (8,8,16): z = b*4 + h-split.
__global__ __launch_bounds__(256) void pair_kernel(
    const float* __restrict__ hid, const float* __restrict__ Wo,
    float* __restrict__ out)
{
    const int t  = threadIdx.x;
    const int b  = blockIdx.z >> 2;
    const int h0 = (blockIdx.z & 3) * 256;
    const int n0 = blockIdx.y * 16;
    const int m0 = blockIdx.x * 16;

    __shared__ float s1[16][260];
    __shared__ float s2[16][260];
    __shared__ float sw[2][256];

    const float* __restrict__ base1 = hid + ((size_t)(b * 128 + n0)) * 1024 + h0;
    const float* __restrict__ base2 = hid + ((size_t)(512 + b * 128 + m0)) * 1024 + h0;

    #pragma unroll
    for (int p = 0; p < 4; ++p) {
        const int slot = p * 256 + t;
        const int r  = slot >> 6;
        const int c  = (slot & 63) << 2;
        *(float4*)&s1[r][c] = *(const float4*)&base1[(size_t)r * 1024 + c];
        *(float4*)&s2[r][c] = *(const float4*)&base2[(size_t)r * 1024 + c];
    }
    if (t < 128) {
        const int o = t >> 6;
        const int c = (t & 63) << 2;
        *(float4*)&sw[o][c] = *(const float4*)&Wo[(size_t)o * 1024 + h0 + c];
    }
    __syncthreads();

    const int i = t >> 4, j = t & 15;
    const float* __restrict__ xrow = &s1[i][0];
    const float* __restrict__ yrow = &s2[j][0];
    float acc0 = 0.f, acc1 = 0.f;

    #pragma unroll 8
    for (int c4 = 0; c4 < 64; ++c4) {
        const float4 x  = *(const float4*)&xrow[c4 * 4];
        const float4 y  = *(const float4*)&yrow[c4 * 4];
        const float4 uu = *(const float4*)&sw[0][c4 * 4];
        const float4 vv = *(const float4*)&sw[1][c4 * 4];
        float r;
        r = fmaxf(x.x + y.x, 0.f); acc0 = fmaf(r, uu.x, acc0); acc1 = fmaf(r, vv.x, acc1);
        r = fmaxf(x.y + y.y, 0.f); acc0 = fmaf(r, uu.y, acc0); acc1 = fmaf(r, vv.y, acc1);
        r = fmaxf(x.z + y.z, 0.f); acc0 = fmaf(r, uu.z, acc0); acc1 = fmaf(r, vv.z, acc1);
        r = fmaxf(x.w + y.w, 0.f); acc0 = fmaf(r, uu.w, acc0); acc1 = fmaf(r, vv.w, acc1);
    }

    const size_t P = (((size_t)b * 128 + n0 + i) * 128 + (m0 + j)) * 2;
    atomicAdd(&out[P],     acc0);
    atomicAdd(&out[P + 1], acc1);
}

extern "C" void kernel_launch(void* const* d_in, const int* in_sizes, int n_in,
                              void* d_out, int out_size, void* d_ws, size_t ws_size,
                              hipStream_t stream) {
    (void)in_sizes; (void)n_in; (void)out_size; (void)ws_size;
    const float* input1 = (const float*)d_in[0];
    const float* input2 = (const float*)d_in[1];
    const float* W1     = (const float*)d_in[2];
    const float* b1     = (const float*)d_in[3];
    const float* W2     = (const float*)d_in[4];
    const float* Wo     = (const float*)d_in[5];
    const float* bo     = (const float*)d_in[6];
    float* out = (float*)d_out;
    float* hid = (float*)d_ws;   // 4 MB

    gemm_mfma<<<dim3(16, 16), 512, 0, stream>>>(input1, input2, W1, W2,
                                                b1, bo, hid, out);
    pair_kernel<<<dim3(8, 8, 16), 256, 0, stream>>>(hid, Wo, out);
}

// Round 12
// 93.716 us; speedup vs baseline: 1.0173x; 1.0173x over previous
//
#include <hip/hip_runtime.h>
#include <hip/hip_bf16.h>

// BiClassifier B=4 N=128 D=768 HID=1024 OUT=2
// R12: R10's proven-best pieces, 3 kernels.
// k1 prepack(+out-init): Abig[1024][768] bf16, Wbig[2][1024][768] bf16;
//     first 65536 threads also write out[gid] = bo (replaces out_init kernel).
// k2 gemm_mfma: hid = Abig @ Wbig[sel].T + b1, in-block split-K x2,
//     gl_lds16 staging + XOR swizzle, dbuf, LDS reduce, plain stores [R10-proven]
// k3 pair: 16x16 pair tile x h-range 256, atomicAdd onto bo-initialized out
//     [R7/R10-proven]

typedef __attribute__((ext_vector_type(8))) short s16x8;
typedef __attribute__((ext_vector_type(4))) float f32x4;

#define KP 768
#define BK 64
#define KHALF 384
#define NSTEP (KHALF / BK)   // 6

__device__ __forceinline__ void gl_lds16(const void* g, void* l) {
    __builtin_amdgcn_global_load_lds(
        (const __attribute__((address_space(1))) unsigned int*)g,
        (__attribute__((address_space(3))) unsigned int*)l, 16, 0, 0);
}

__global__ __launch_bounds__(256) void prepack(
    const float* __restrict__ in1, const float* __restrict__ in2,
    const float* __restrict__ W1, const float* __restrict__ W2,
    const float* __restrict__ bo, float* __restrict__ out,
    ushort* __restrict__ Abig, ushort* __restrict__ Wbig)
{
    const int gid = blockIdx.x * 256 + threadIdx.x;   // 589824 total
    if (gid < 65536) {
        *(float2*)&out[(size_t)gid * 2] = make_float2(bo[0], bo[1]);
    }
    const int src = gid / 196608;                     // 0:A 1:W1 2:W2
    const int rem = gid % 196608;
    const int row = rem / 192;
    const int k4  = (rem % 192) * 4;
    const float* sp;
    ushort* dst;
    if (src == 0) {
        sp  = (row < 512) ? in1 + (size_t)row * 768 + k4
                          : in2 + (size_t)(row - 512) * 768 + k4;
        dst = Abig + (size_t)row * KP + k4;
    } else {
        sp  = (src == 1 ? W1 : W2) + (size_t)row * 768 + k4;
        dst = Wbig + (size_t)(src - 1) * (1024 * KP) + (size_t)row * KP + k4;
    }
    const float4 x = *(const float4*)sp;
    const float xf[4] = {x.x, x.y, x.z, x.w};
    ushort h[4];
    #pragma unroll
    for (int i = 0; i < 4; ++i) {
        __hip_bfloat16 bh = __float2bfloat16(xf[i]);
        h[i] = *(ushort*)&bh;
    }
    *(ushort4*)dst = make_ushort4(h[0], h[1], h[2], h[3]);
}

// 64x64 tile, 512 thr = 8 waves: w>>2 = K-half, w&3 = space wave (2x2 of 32x32).
// Double-buffered gl_lds16 staging (swizzle-inverse global src, linear LDS dest,
// XOR-swizzled reads). LDS cross-wave K-reduce epilogue, plain stores.
__global__ __launch_bounds__(512) void gemm_mfma(
    const ushort* __restrict__ Abig, const ushort* __restrict__ Wbig,
    const float* __restrict__ b1, float* __restrict__ hid)
{
    const int t    = threadIdx.x;
    const int lane = t & 63;
    const int w    = t >> 6;
    const int kh   = w >> 2;        // K-half 0/1
    const int ws   = w & 3;         // space wave
    const int row0 = blockIdx.y * 64;
    const int col0 = blockIdx.x * 64;

    const char* __restrict__ A = (const char*)(Abig + (size_t)row0 * KP);
    const char* __restrict__ W = (const char*)(Wbig
                                   + (row0 < 512 ? (size_t)0 : (size_t)1024 * KP)
                                   + (size_t)col0 * KP);

    __shared__ ushort lds[2][2][2][4096];   // [buf][kh][A/W][8KB] = 64KB

    const int srow = t >> 3;
    const int kbyt = (((t & 7) ^ (srow & 7)) << 4);
    const size_t rowoff = (size_t)srow * (KP * 2);

    const int wr = ws >> 1, wc = ws & 1;
    const int l15 = lane & 15, kg = lane >> 4;
    int aoff[2][2], boff[2][2];   // [kk][frag]
    #pragma unroll
    for (int kk = 0; kk < 2; ++kk)
        #pragma unroll
        for (int f = 0; f < 2; ++f) {
            const int r = wr * 32 + f * 16 + l15;
            const int c = wc * 32 + f * 16 + l15;
            const int sw_ = kk * 64 + kg * 16;
            aoff[kk][f] = r * 128 + (sw_ ^ ((r & 7) << 4));
            boff[kk][f] = c * 128 + (sw_ ^ ((c & 7) << 4));
        }

#define STAGE(buf, ktk) do {                                                   \
        const size_t kby = (size_t)(ktk) * (BK * 2);                           \
        _Pragma("unroll")                                                      \
        for (int p = 0; p < 4; ++p) {                                          \
            const char* src = (p & 1) ? W : A;                                 \
            const size_t off = rowoff + (size_t)(p >> 1) * (KHALF * 2)         \
                               + kby + kbyt;                                   \
            gl_lds16(src + off,                                                \
                     (char*)&lds[buf][p >> 1][p & 1][0] + t * 16);             \
        }                                                                      \
    } while (0)

    const f32x4 zero = {0.f, 0.f, 0.f, 0.f};
    f32x4 acc[2][2] = {{zero, zero}, {zero, zero}};

    STAGE(0, 0);
    int cur = 0;
    for (int kt = 0; kt < NSTEP; ++kt) {
        asm volatile("s_waitcnt vmcnt(0)" ::: "memory");
        __syncthreads();
        if (kt + 1 < NSTEP) STAGE(cur ^ 1, kt + 1);
        const char* __restrict__ ab = (const char*)&lds[cur][kh][0][0];
        const char* __restrict__ wb = (const char*)&lds[cur][kh][1][0];
        #pragma unroll
        for (int kk = 0; kk < 2; ++kk) {
            s16x8 af[2], bf_[2];
            #pragma unroll
            for (int f = 0; f < 2; ++f) {
                af[f]  = *(const s16x8*)(ab + aoff[kk][f]);
                bf_[f] = *(const s16x8*)(wb + boff[kk][f]);
            }
            #pragma unroll
            for (int fr = 0; fr < 2; ++fr)
                #pragma unroll
                for (int fc = 0; fc < 2; ++fc)
                    acc[fr][fc] = __builtin_amdgcn_mfma_f32_16x16x32_bf16(
                        af[fr], bf_[fc], acc[fr][fc], 0, 0, 0);
        }
        cur ^= 1;
    }
#undef STAGE

    __syncthreads();
    float* red = (float*)&lds[0][0][0][0];
    if (kh == 1) {
        #pragma unroll
        for (int fr = 0; fr < 2; ++fr)
            #pragma unroll
            for (int fc = 0; fc < 2; ++fc)
                *(f32x4*)&red[(((ws * 2 + fr) * 2 + fc) * 64 + lane) * 4] =
                    acc[fr][fc];
    }
    __syncthreads();
    if (kh == 0) {
        float bias[2] = {0.f, 0.f};
        if (row0 < 512) {
            bias[0] = b1[col0 + wc * 32 + l15];
            bias[1] = b1[col0 + wc * 32 + 16 + l15];
        }
        #pragma unroll
        for (int fr = 0; fr < 2; ++fr)
            #pragma unroll
            for (int fc = 0; fc < 2; ++fc) {
                const f32x4 o = *(const f32x4*)
                    &red[(((ws * 2 + fr) * 2 + fc) * 64 + lane) * 4];
                #pragma unroll
                for (int i = 0; i < 4; ++i) {
                    const int r = row0 + wr * 32 + fr * 16 + kg * 4 + i;
                    const int c = col0 + wc * 32 + fc * 16 + l15;
                    hid[(size_t)r * 1024 + c] = acc[fr][fc][i] + o[i] + bias[fc];
                }
            }
    }
}

// 16x16 pair tile x h-range 256. Grid (8,8,16): z = b*4 + h-split.
__global__ __launch_bounds__(256) void pair_kernel(
    const float* __restrict__ hid, const float* __restrict__ Wo,
    float* __restrict__ out)
{
    const int t  = threadIdx.x;
    const int b  = blockIdx.z >> 2;
    const int h0 = (blockIdx.z & 3) * 256;
    const int n0 = blockIdx.y * 16;
    const int m0 = blockIdx.x * 16;

    __shared__ float s1[16][260];
    __shared__ float s2[16][260];
    __shared__ float sw[2][256];

    const float* __restrict__ base1 = hid + ((size_t)(b * 128 + n0)) * 1024 + h0;
    const float* __restrict__ base2 = hid + ((size_t)(512 + b * 128 + m0)) * 1024 + h0;

    #pragma unroll
    for (int p = 0; p < 4; ++p) {
        const int slot = p * 256 + t;
        const int r  = slot >> 6;
        const int c  = (slot & 63) << 2;
        *(float4*)&s1[r][c] = *(const float4*)&base1[(size_t)r * 1024 + c];
        *(float4*)&s2[r][c] = *(const float4*)&base2[(size_t)r * 1024 + c];
    }
    if (t < 128) {
        const int o = t >> 6;
        const int c = (t & 63) << 2;
        *(float4*)&sw[o][c] = *(const float4*)&Wo[(size_t)o * 1024 + h0 + c];
    }
    __syncthreads();

    const int i = t >> 4, j = t & 15;
    const float* __restrict__ xrow = &s1[i][0];
    const float* __restrict__ yrow = &s2[j][0];
    float acc0 = 0.f, acc1 = 0.f;

    #pragma unroll 8
    for (int c4 = 0; c4 < 64; ++c4) {
        const float4 x  = *(const float4*)&xrow[c4 * 4];
        const float4 y  = *(const float4*)&yrow[c4 * 4];
        const float4 uu = *(const float4*)&sw[0][c4 * 4];
        const float4 vv = *(const float4*)&sw[1][c4 * 4];
        float r;
        r = fmaxf(x.x + y.x, 0.f); acc0 = fmaf(r, uu.x, acc0); acc1 = fmaf(r, vv.x, acc1);
        r = fmaxf(x.y + y.y, 0.f); acc0 = fmaf(r, uu.y, acc0); acc1 = fmaf(r, vv.y, acc1);
        r = fmaxf(x.z + y.z, 0.f); acc0 = fmaf(r, uu.z, acc0); acc1 = fmaf(r, vv.z, acc1);
        r = fmaxf(x.w + y.w, 0.f); acc0 = fmaf(r, uu.w, acc0); acc1 = fmaf(r, vv.w, acc1);
    }

    const size_t P = (((size_t)b * 128 + n0 + i) * 128 + (m0 + j)) * 2;
    atomicAdd(&out[P],     acc0);
    atomicAdd(&out[P + 1], acc1);
}

extern "C" void kernel_launch(void* const* d_in, const int* in_sizes, int n_in,
                              void* d_out, int out_size, void* d_ws, size_t ws_size,
                              hipStream_t stream) {
    (void)in_sizes; (void)n_in; (void)out_size; (void)ws_size;
    const float* input1 = (const float*)d_in[0];
    const float* input2 = (const float*)d_in[1];
    const float* W1     = (const float*)d_in[2];
    const float* b1     = (const float*)d_in[3];
    const float* W2     = (const float*)d_in[4];
    const float* Wo     = (const float*)d_in[5];
    const float* bo     = (const float*)d_in[6];
    float* out = (float*)d_out;

    ushort* Abig = (ushort*)d_ws;                           // 1.5 MB
    ushort* Wbig = Abig + (size_t)1024 * KP;                // 3 MB
    float*  hid  = (float*)(Wbig + (size_t)2 * 1024 * KP);  // 4 MB

    prepack<<<2304, 256, 0, stream>>>(input1, input2, W1, W2, bo, out, Abig, Wbig);
    gemm_mfma<<<dim3(16, 16), 512, 0, stream>>>(Abig, Wbig, b1, hid);
    pair_kernel<<<dim3(8, 8, 16), 256, 0, stream>>>(hid, Wo, out);
}

// Round 13
// 92.617 us; speedup vs baseline: 1.0294x; 1.0119x over previous
//
#include <hip/hip_runtime.h>
#include <hip/hip_bf16.h>

// BiClassifier B=4 N=128 D=768 HID=1024 OUT=2
// R13: R12 with pair register-tiled (2x2 per thread) — LDS-issue-bound -> VALU-bound.
// k1 prepack(+out-init): bf16 convert; first 65536 threads write out = bo [R12]
// k2 gemm_mfma: hid = Abig @ Wbig[sel].T + b1, in-block split-K x2 [R10/R12-proven]
// k3 pair: 32x32 pair tile x h-range 128, 2x2/thread (rows {i,i+16} x cols {j,j+16}),
//          grid (4,16,8) = 512 blocks, atomicAdd onto bo-initialized out.

typedef __attribute__((ext_vector_type(8))) short s16x8;
typedef __attribute__((ext_vector_type(4))) float f32x4;

#define KP 768
#define BK 64
#define KHALF 384
#define NSTEP (KHALF / BK)   // 6

__device__ __forceinline__ void gl_lds16(const void* g, void* l) {
    __builtin_amdgcn_global_load_lds(
        (const __attribute__((address_space(1))) unsigned int*)g,
        (__attribute__((address_space(3))) unsigned int*)l, 16, 0, 0);
}

__global__ __launch_bounds__(256) void prepack(
    const float* __restrict__ in1, const float* __restrict__ in2,
    const float* __restrict__ W1, const float* __restrict__ W2,
    const float* __restrict__ bo, float* __restrict__ out,
    ushort* __restrict__ Abig, ushort* __restrict__ Wbig)
{
    const int gid = blockIdx.x * 256 + threadIdx.x;   // 589824 total
    if (gid < 65536) {
        *(float2*)&out[(size_t)gid * 2] = make_float2(bo[0], bo[1]);
    }
    const int src = gid / 196608;                     // 0:A 1:W1 2:W2
    const int rem = gid % 196608;
    const int row = rem / 192;
    const int k4  = (rem % 192) * 4;
    const float* sp;
    ushort* dst;
    if (src == 0) {
        sp  = (row < 512) ? in1 + (size_t)row * 768 + k4
                          : in2 + (size_t)(row - 512) * 768 + k4;
        dst = Abig + (size_t)row * KP + k4;
    } else {
        sp  = (src == 1 ? W1 : W2) + (size_t)row * 768 + k4;
        dst = Wbig + (size_t)(src - 1) * (1024 * KP) + (size_t)row * KP + k4;
    }
    const float4 x = *(const float4*)sp;
    const float xf[4] = {x.x, x.y, x.z, x.w};
    ushort h[4];
    #pragma unroll
    for (int i = 0; i < 4; ++i) {
        __hip_bfloat16 bh = __float2bfloat16(xf[i]);
        h[i] = *(ushort*)&bh;
    }
    *(ushort4*)dst = make_ushort4(h[0], h[1], h[2], h[3]);
}

// 64x64 tile, 512 thr = 8 waves: w>>2 = K-half, w&3 = space wave (2x2 of 32x32).
__global__ __launch_bounds__(512) void gemm_mfma(
    const ushort* __restrict__ Abig, const ushort* __restrict__ Wbig,
    const float* __restrict__ b1, float* __restrict__ hid)
{
    const int t    = threadIdx.x;
    const int lane = t & 63;
    const int w    = t >> 6;
    const int kh   = w >> 2;        // K-half 0/1
    const int ws   = w & 3;         // space wave
    const int row0 = blockIdx.y * 64;
    const int col0 = blockIdx.x * 64;

    const char* __restrict__ A = (const char*)(Abig + (size_t)row0 * KP);
    const char* __restrict__ W = (const char*)(Wbig
                                   + (row0 < 512 ? (size_t)0 : (size_t)1024 * KP)
                                   + (size_t)col0 * KP);

    __shared__ ushort lds[2][2][2][4096];   // [buf][kh][A/W][8KB] = 64KB

    const int srow = t >> 3;
    const int kbyt = (((t & 7) ^ (srow & 7)) << 4);
    const size_t rowoff = (size_t)srow * (KP * 2);

    const int wr = ws >> 1, wc = ws & 1;
    const int l15 = lane & 15, kg = lane >> 4;
    int aoff[2][2], boff[2][2];   // [kk][frag]
    #pragma unroll
    for (int kk = 0; kk < 2; ++kk)
        #pragma unroll
        for (int f = 0; f < 2; ++f) {
            const int r = wr * 32 + f * 16 + l15;
            const int c = wc * 32 + f * 16 + l15;
            const int sw_ = kk * 64 + kg * 16;
            aoff[kk][f] = r * 128 + (sw_ ^ ((r & 7) << 4));
            boff[kk][f] = c * 128 + (sw_ ^ ((c & 7) << 4));
        }

#define STAGE(buf, ktk) do {                                                   \
        const size_t kby = (size_t)(ktk) * (BK * 2);                           \
        _Pragma("unroll")                                                      \
        for (int p = 0; p < 4; ++p) {                                          \
            const char* src = (p & 1) ? W : A;                                 \
            const size_t off = rowoff + (size_t)(p >> 1) * (KHALF * 2)         \
                               + kby + kbyt;                                   \
            gl_lds16(src + off,                                                \
                     (char*)&lds[buf][p >> 1][p & 1][0] + t * 16);             \
        }                                                                      \
    } while (0)

    const f32x4 zero = {0.f, 0.f, 0.f, 0.f};
    f32x4 acc[2][2] = {{zero, zero}, {zero, zero}};

    STAGE(0, 0);
    int cur = 0;
    for (int kt = 0; kt < NSTEP; ++kt) {
        asm volatile("s_waitcnt vmcnt(0)" ::: "memory");
        __syncthreads();
        if (kt + 1 < NSTEP) STAGE(cur ^ 1, kt + 1);
        const char* __restrict__ ab = (const char*)&lds[cur][kh][0][0];
        const char* __restrict__ wb = (const char*)&lds[cur][kh][1][0];
        #pragma unroll
        for (int kk = 0; kk < 2; ++kk) {
            s16x8 af[2], bf_[2];
            #pragma unroll
            for (int f = 0; f < 2; ++f) {
                af[f]  = *(const s16x8*)(ab + aoff[kk][f]);
                bf_[f] = *(const s16x8*)(wb + boff[kk][f]);
            }
            #pragma unroll
            for (int fr = 0; fr < 2; ++fr)
                #pragma unroll
                for (int fc = 0; fc < 2; ++fc)
                    acc[fr][fc] = __builtin_amdgcn_mfma_f32_16x16x32_bf16(
                        af[fr], bf_[fc], acc[fr][fc], 0, 0, 0);
        }
        cur ^= 1;
    }
#undef STAGE

    __syncthreads();
    float* red = (float*)&lds[0][0][0][0];
    if (kh == 1) {
        #pragma unroll
        for (int fr = 0; fr < 2; ++fr)
            #pragma unroll
            for (int fc = 0; fc < 2; ++fc)
                *(f32x4*)&red[(((ws * 2 + fr) * 2 + fc) * 64 + lane) * 4] =
                    acc[fr][fc];
    }
    __syncthreads();
    if (kh == 0) {
        float bias[2] = {0.f, 0.f};
        if (row0 < 512) {
            bias[0] = b1[col0 + wc * 32 + l15];
            bias[1] = b1[col0 + wc * 32 + 16 + l15];
        }
        #pragma unroll
        for (int fr = 0; fr < 2; ++fr)
            #pragma unroll
            for (int fc = 0; fc < 2; ++fc) {
                const f32x4 o = *(const f32x4*)
                    &red[(((ws * 2 + fr) * 2 + fc) * 64 + lane) * 4];
                #pragma unroll
                for (int i = 0; i < 4; ++i) {
                    const int r = row0 + wr * 32 + fr * 16 + kg * 4 + i;
                    const int c = col0 + wc * 32 + fc * 16 + l15;
                    hid[(size_t)r * 1024 + c] = acc[fr][fc][i] + o[i] + bias[fc];
                }
            }
    }
}

// 32x32 pair tile x h-range 128; 2x2 pairs/thread (rows {i,i+16} x cols {j,j+16}).
// Grid (4, 16, 8): x = m-tile, y = b*4 + n-tile, z = h-split. 512 blocks.
__global__ __launch_bounds__(256) void pair_kernel(
    const float* __restrict__ hid, const float* __restrict__ Wo,
    float* __restrict__ out)
{
    const int t  = threadIdx.x;
    const int h0 = blockIdx.z * 128;
    const int b  = blockIdx.y >> 2;
    const int n0 = (blockIdx.y & 3) * 32;
    const int m0 = blockIdx.x * 32;

    __shared__ float s1[32][132];   // +4 pad: 16-row-split reads stay 2-way (free)
    __shared__ float s2[32][132];
    __shared__ float sw[2][128];

    const float* __restrict__ base1 = hid + ((size_t)(b * 128 + n0)) * 1024 + h0;
    const float* __restrict__ base2 = hid + ((size_t)(512 + b * 128 + m0)) * 1024 + h0;

    // stage 32 rows x 128 floats per tensor: slot = p*256+t -> r = slot>>5, c = (slot&31)*4
    #pragma unroll
    for (int p = 0; p < 4; ++p) {
        const int slot = p * 256 + t;
        const int r = slot >> 5;
        const int c = (slot & 31) << 2;
        *(float4*)&s1[r][c] = *(const float4*)&base1[(size_t)r * 1024 + c];
        *(float4*)&s2[r][c] = *(const float4*)&base2[(size_t)r * 1024 + c];
    }
    if (t < 64) {
        const int o = t >> 5;
        const int c = (t & 31) << 2;
        *(float4*)&sw[o][c] = *(const float4*)&Wo[(size_t)o * 1024 + h0 + c];
    }
    __syncthreads();

    const int i = t >> 4, j = t & 15;   // rows i, i+16; cols j, j+16
    float acc[2][2][2] = {};            // [n][m][o]

    #pragma unroll 4
    for (int c4 = 0; c4 < 32; ++c4) {
        const int c = c4 << 2;
        const float4 x0 = *(const float4*)&s1[i][c];
        const float4 x1 = *(const float4*)&s1[i + 16][c];
        const float4 y0 = *(const float4*)&s2[j][c];
        const float4 y1 = *(const float4*)&s2[j + 16][c];
        const float4 u  = *(const float4*)&sw[0][c];
        const float4 v  = *(const float4*)&sw[1][c];
        #pragma unroll
        for (int k = 0; k < 4; ++k) {
            const float xk0 = ((const float*)&x0)[k];
            const float xk1 = ((const float*)&x1)[k];
            const float yk0 = ((const float*)&y0)[k];
            const float yk1 = ((const float*)&y1)[k];
            const float uk  = ((const float*)&u)[k];
            const float vk  = ((const float*)&v)[k];
            const float r00 = fmaxf(xk0 + yk0, 0.f);
            const float r01 = fmaxf(xk0 + yk1, 0.f);
            const float r10 = fmaxf(xk1 + yk0, 0.f);
            const float r11 = fmaxf(xk1 + yk1, 0.f);
            acc[0][0][0] = fmaf(r00, uk, acc[0][0][0]);
            acc[0][0][1] = fmaf(r00, vk, acc[0][0][1]);
            acc[0][1][0] = fmaf(r01, uk, acc[0][1][0]);
            acc[0][1][1] = fmaf(r01, vk, acc[0][1][1]);
            acc[1][0][0] = fmaf(r10, uk, acc[1][0][0]);
            acc[1][0][1] = fmaf(r10, vk, acc[1][0][1]);
            acc[1][1][0] = fmaf(r11, uk, acc[1][1][0]);
            acc[1][1][1] = fmaf(r11, vk, acc[1][1][1]);
        }
    }

    #pragma unroll
    for (int ni = 0; ni < 2; ++ni)
        #pragma unroll
        for (int mj = 0; mj < 2; ++mj) {
            const size_t P = ((size_t)(b * 128 + n0 + i + ni * 16)) * 128
                             + (m0 + j + mj * 16);
            atomicAdd(&out[P * 2],     acc[ni][mj][0]);
            atomicAdd(&out[P * 2 + 1], acc[ni][mj][1]);
        }
}

extern "C" void kernel_launch(void* const* d_in, const int* in_sizes, int n_in,
                              void* d_out, int out_size, void* d_ws, size_t ws_size,
                              hipStream_t stream) {
    (void)in_sizes; (void)n_in; (void)out_size; (void)ws_size;
    const float* input1 = (const float*)d_in[0];
    const float* input2 = (const float*)d_in[1];
    const float* W1     = (const float*)d_in[2];
    const float* b1     = (const float*)d_in[3];
    const float* W2     = (const float*)d_in[4];
    const float* Wo     = (const float*)d_in[5];
    const float* bo     = (const float*)d_in[6];
    float* out = (float*)d_out;

    ushort* Abig = (ushort*)d_ws;                           // 1.5 MB
    ushort* Wbig = Abig + (size_t)1024 * KP;                // 3 MB
    float*  hid  = (float*)(Wbig + (size_t)2 * 1024 * KP);  // 4 MB

    prepack<<<2304, 256, 0, stream>>>(input1, input2, W1, W2, bo, out, Abig, Wbig);
    gemm_mfma<<<dim3(16, 16), 512, 0, stream>>>(Abig, Wbig, b1, hid);
    pair_kernel<<<dim3(4, 16, 8), 256, 0, stream>>>(hid, Wo, out);
}